// Round 1
// baseline (251.161 us; speedup 1.0000x reference)
//
#include <hip/hip_runtime.h>
#include <math.h>

#define NN 768
#define DD 128
#define AA 312
#define HH 8
#define CEPS 1e-8f

__device__ __forceinline__ float wave_sum(float v) {
    #pragma unroll
    for (int o = 32; o; o >>= 1) v += __shfl_down(v, o, 64);
    return v;
}
__device__ __forceinline__ float wave_max(float v) {
    #pragma unroll
    for (int o = 32; o; o >>= 1) v = fmaxf(v, __shfl_down(v, o, 64));
    return v;
}

// Row L2 norms: one wave per row.
__global__ __launch_bounds__(64) void norms_kernel(const float* __restrict__ X, int cols,
                                                   float* __restrict__ nrm) {
    const int row = blockIdx.x;
    const float* x = X + (size_t)row * cols;
    float s = 0.f;
    for (int c = threadIdx.x; c < cols; c += 64) { float v = x[c]; s += v * v; }
    s = wave_sum(s);
    if (threadIdx.x == 0) nrm[row] = sqrtf(s);
}

// 32x32 tiled transpose. rows must be a multiple of 32 (true for 768 and 128); cols guarded.
__global__ __launch_bounds__(256) void transpose_kernel(const float* __restrict__ X, int rows,
                                                        int cols, float* __restrict__ Xt) {
    __shared__ float tile[32][33];
    const int c0 = blockIdx.x * 32, r0 = blockIdx.y * 32;
    const int tx = threadIdx.x & 31, ty = threadIdx.x >> 5;
    #pragma unroll
    for (int rr = ty; rr < 32; rr += 8) {
        int c = c0 + tx;
        if (c < cols) tile[rr][tx] = X[(size_t)(r0 + rr) * cols + c];
    }
    __syncthreads();
    #pragma unroll
    for (int rr = ty; rr < 32; rr += 8) {
        int c = c0 + rr;
        if (c < cols) Xt[(size_t)c * rows + (r0 + tx)] = tile[tx][rr];
    }
}

// E[i,:] = softmax(cos_sim(x_i, x_j) * invtemp). One block per row i; Xt is [COLS][N].
template <int COLS>
__global__ __launch_bounds__(256) void init_edge_kernel(const float* __restrict__ Xt,
                                                        const float* __restrict__ nrm,
                                                        float invtemp, float* __restrict__ E) {
    const int i = blockIdx.x;
    const int tid = threadIdx.x;
    __shared__ float xi[COLS];
    __shared__ float redA[4], redB[4];
    for (int c = tid; c < COLS; c += 256) xi[c] = Xt[(size_t)c * NN + i];
    __syncthreads();
    float d0 = 0.f, d1 = 0.f, d2 = 0.f;
    for (int c = 0; c < COLS; ++c) {
        const float xc = xi[c];
        const float* xr = Xt + (size_t)c * NN;
        d0 = fmaf(xc, xr[tid], d0);
        d1 = fmaf(xc, xr[tid + 256], d1);
        d2 = fmaf(xc, xr[tid + 512], d2);
    }
    const float ni = nrm[i];
    float v0 = d0 / fmaxf(ni * nrm[tid], CEPS) * invtemp;
    float v1 = d1 / fmaxf(ni * nrm[tid + 256], CEPS) * invtemp;
    float v2 = d2 / fmaxf(ni * nrm[tid + 512], CEPS) * invtemp;
    float m = wave_max(fmaxf(fmaxf(v0, v1), v2));
    if ((tid & 63) == 0) redA[tid >> 6] = m;
    __syncthreads();
    m = fmaxf(fmaxf(redA[0], redA[1]), fmaxf(redA[2], redA[3]));
    float e0 = __expf(v0 - m), e1 = __expf(v1 - m), e2 = __expf(v2 - m);
    float s = wave_sum(e0 + e1 + e2);
    if ((tid & 63) == 0) redB[tid >> 6] = s;
    __syncthreads();
    s = redB[0] + redB[1] + redB[2] + redB[3];
    const float inv = 1.f / s;
    float* Er = E + (size_t)i * NN;
    Er[tid] = e0 * inv;
    Er[tid + 256] = e1 * inv;
    Er[tid + 512] = e2 * inv;
}

// out = relu(LN((Ep@P + Ex@P) @ W^T + b, g, beta)) + Ep@P.  One block (128 thr) per row i.
// WT is W transposed ([c][d]) so the projection reads coalesced.
__global__ __launch_bounds__(128) void node_update_kernel(
    const float* __restrict__ P, const float* __restrict__ Ep, const float* __restrict__ Ex,
    const float* __restrict__ WT, const float* __restrict__ b, const float* __restrict__ g,
    const float* __restrict__ beta, float* __restrict__ out, float* __restrict__ outT) {
    const int i = blockIdx.x;
    const int d = threadIdx.x;
    __shared__ float ep[NN], ex[NN], q[DD];
    __shared__ float redA[2], redB[2];
    for (int k = d; k < NN; k += DD) {
        ep[k] = Ep[(size_t)i * NN + k];
        ex[k] = Ex[(size_t)i * NN + k];
    }
    __syncthreads();
    float p = 0.f, x = 0.f;
    for (int k = 0; k < NN; ++k) {
        float pv = P[(size_t)k * DD + d];  // coalesced across threads
        p = fmaf(ep[k], pv, p);
        x = fmaf(ex[k], pv, x);
    }
    q[d] = p + x;
    __syncthreads();
    float t = b[d];
    for (int c = 0; c < DD; ++c) t = fmaf(q[c], WT[(size_t)c * DD + d], t);
    float s = wave_sum(t);
    if ((d & 63) == 0) redA[d >> 6] = s;
    __syncthreads();
    const float mean = (redA[0] + redA[1]) * (1.f / DD);
    const float dv = t - mean;
    float s2 = wave_sum(dv * dv);
    if ((d & 63) == 0) redB[d >> 6] = s2;
    __syncthreads();
    const float var = (redB[0] + redB[1]) * (1.f / DD);
    const float ln = dv * rsqrtf(var + 1e-5f) * g[d] + beta[d];
    const float val = fmaxf(ln, 0.f) + p;
    out[(size_t)i * DD + d] = val;
    outT[(size_t)d * NN + i] = val;
}

__device__ __forceinline__ float edge_mlp_tail(float* z, const float* __restrict__ b1,
                                               const float* __restrict__ W2, float b2s) {
    float mean = 0.f;
    #pragma unroll
    for (int r = 0; r < HH; ++r) { z[r] += b1[r]; mean += z[r]; }
    mean *= (1.f / HH);
    float var = 0.f;
    #pragma unroll
    for (int r = 0; r < HH; ++r) { float dv = z[r] - mean; var += dv * dv; }
    var *= (1.f / HH);
    const float istd = rsqrtf(var + 1e-5f);
    float acc = b2s;
    #pragma unroll
    for (int r = 0; r < HH; ++r) {
        float hn = fmaxf((z[r] - mean) * istd, 0.f);
        acc = fmaf(hn, W2[r], acc);
    }
    return tanhf(acc);
}

// E2[i,:] = softmax(tanh(MLP((p_i - p_j)^2)) * (lastE[i,:]+eps) * invtemp). Block per row i.
__global__ __launch_bounds__(256) void edge_update_kernel(
    const float* __restrict__ PR, const float* __restrict__ PRt, const float* __restrict__ lastE,
    const float* __restrict__ W1, const float* __restrict__ b1, const float* __restrict__ W2,
    const float* __restrict__ b2, float invtemp, float* __restrict__ E2) {
    const int i = blockIdx.x;
    const int tid = threadIdx.x;
    __shared__ float pi[DD];
    __shared__ float redA[4], redB[4];
    if (tid < DD) pi[tid] = PR[(size_t)i * DD + tid];
    __syncthreads();
    const int j0 = tid, j1 = tid + 256, j2 = tid + 512;
    float z0[HH], z1[HH], z2[HH];
    #pragma unroll
    for (int r = 0; r < HH; ++r) { z0[r] = 0.f; z1[r] = 0.f; z2[r] = 0.f; }
    const float4* w4 = (const float4*)W1;  // wave-uniform index -> scalar loads
    const float4* p4 = (const float4*)pi;
    for (int k4 = 0; k4 < DD / 4; ++k4) {
        const float4 pv = p4[k4];
        const float* r0 = PRt + (size_t)(k4 * 4) * NN;
        const float* r1 = r0 + NN;
        const float* r2 = r1 + NN;
        const float* r3 = r2 + NN;
        float q00 = pv.x - r0[j0]; q00 *= q00;
        float q10 = pv.x - r0[j1]; q10 *= q10;
        float q20 = pv.x - r0[j2]; q20 *= q20;
        float q01 = pv.y - r1[j0]; q01 *= q01;
        float q11 = pv.y - r1[j1]; q11 *= q11;
        float q21 = pv.y - r1[j2]; q21 *= q21;
        float q02 = pv.z - r2[j0]; q02 *= q02;
        float q12 = pv.z - r2[j1]; q12 *= q12;
        float q22 = pv.z - r2[j2]; q22 *= q22;
        float q03 = pv.w - r3[j0]; q03 *= q03;
        float q13 = pv.w - r3[j1]; q13 *= q13;
        float q23 = pv.w - r3[j2]; q23 *= q23;
        #pragma unroll
        for (int r = 0; r < HH; ++r) {
            const float4 w = w4[r * (DD / 4) + k4];
            z0[r] += w.x * q00 + w.y * q01 + w.z * q02 + w.w * q03;
            z1[r] += w.x * q10 + w.y * q11 + w.z * q12 + w.w * q13;
            z2[r] += w.x * q20 + w.y * q21 + w.z * q22 + w.w * q23;
        }
    }
    const float b2s = b2[0];
    const float* lrow = lastE + (size_t)i * NN;
    float v0 = edge_mlp_tail(z0, b1, W2, b2s) * (lrow[j0] + CEPS) * invtemp;
    float v1 = edge_mlp_tail(z1, b1, W2, b2s) * (lrow[j1] + CEPS) * invtemp;
    float v2 = edge_mlp_tail(z2, b1, W2, b2s) * (lrow[j2] + CEPS) * invtemp;
    float m = wave_max(fmaxf(fmaxf(v0, v1), v2));
    if ((tid & 63) == 0) redA[tid >> 6] = m;
    __syncthreads();
    m = fmaxf(fmaxf(redA[0], redA[1]), fmaxf(redA[2], redA[3]));
    float e0 = __expf(v0 - m), e1 = __expf(v1 - m), e2 = __expf(v2 - m);
    float s = wave_sum(e0 + e1 + e2);
    if ((tid & 63) == 0) redB[tid >> 6] = s;
    __syncthreads();
    s = redB[0] + redB[1] + redB[2] + redB[3];
    const float inv = 1.f / s;
    float* Er = E2 + (size_t)i * NN;
    Er[j0] = e0 * inv;
    Er[j1] = e1 * inv;
    Er[j2] = e2 * inv;
}

extern "C" void kernel_launch(void* const* d_in, const int* in_sizes, int n_in, void* d_out,
                              int out_size, void* d_ws, size_t ws_size, hipStream_t stream) {
    const float* visual    = (const float*)d_in[0];
    const float* semantic  = (const float*)d_in[1];
    const float* attribute = (const float*)d_in[2];
    const float* Wvn  = (const float*)d_in[3];
    const float* bvn  = (const float*)d_in[4];
    const float* gvn  = (const float*)d_in[5];
    const float* betavn = (const float*)d_in[6];
    const float* Wve1 = (const float*)d_in[7];
    const float* bve1 = (const float*)d_in[8];
    const float* Wve2 = (const float*)d_in[9];
    const float* bve2 = (const float*)d_in[10];
    const float* Wsn  = (const float*)d_in[11];
    const float* bsn  = (const float*)d_in[12];
    const float* gsn  = (const float*)d_in[13];
    const float* betasn = (const float*)d_in[14];
    const float* Wse1 = (const float*)d_in[15];
    const float* bse1 = (const float*)d_in[16];
    const float* Wse2 = (const float*)d_in[17];
    const float* bse2 = (const float*)d_in[18];

    float* out = (float*)d_out;
    float* vp  = out;              // 768*128
    float* sp  = out + 98304;      // 768*128
    float* ve2 = out + 196608;     // 768*768
    float* se2 = out + 786432;     // 768*768

    float* ws    = (float*)d_ws;
    float* nrm_v = ws;             // 768
    float* nrm_a = ws + 768;       // 768
    float* Vt    = ws + 1536;      // 128*768
    float* At    = ws + 99840;     // 312*768
    float* ve    = ws + 339456;    // 768*768
    float* se    = ws + 929280;    // 768*768
    float* vpT   = ws + 1519104;   // 128*768
    float* spT   = ws + 1617408;   // 128*768
    float* WvnT  = ws + 1715712;   // 128*128
    float* WsnT  = ws + 1732096;   // 128*128

    norms_kernel<<<NN, 64, 0, stream>>>(visual, DD, nrm_v);
    norms_kernel<<<NN, 64, 0, stream>>>(attribute, AA, nrm_a);
    transpose_kernel<<<dim3(4, 24), 256, 0, stream>>>(visual, NN, DD, Vt);
    transpose_kernel<<<dim3(10, 24), 256, 0, stream>>>(attribute, NN, AA, At);
    transpose_kernel<<<dim3(4, 4), 256, 0, stream>>>(Wvn, DD, DD, WvnT);
    transpose_kernel<<<dim3(4, 4), 256, 0, stream>>>(Wsn, DD, DD, WsnT);

    init_edge_kernel<DD><<<NN, 256, 0, stream>>>(Vt, nrm_v, 10.f, ve);
    init_edge_kernel<AA><<<NN, 256, 0, stream>>>(At, nrm_a, 10.f, se);

    node_update_kernel<<<NN, 128, 0, stream>>>(visual, ve, se, WvnT, bvn, gvn, betavn, vp, vpT);
    edge_update_kernel<<<NN, 256, 0, stream>>>(vp, vpT, ve, Wve1, bve1, Wve2, bve2, 0.1f, ve2);
    node_update_kernel<<<NN, 128, 0, stream>>>(semantic, se, ve2, WsnT, bsn, gsn, betasn, sp, spT);
    edge_update_kernel<<<NN, 256, 0, stream>>>(sp, spT, se, Wse1, bse1, Wse2, bse2, 0.1f, se2);
}

// Round 2
// 244.050 us; speedup vs baseline: 1.0291x; 1.0291x over previous
//
#include <hip/hip_runtime.h>
#include <math.h>

#define NN 768
#define DD 128
#define AA 312
#define HH 8
#define CEPS 1e-8f

__device__ __forceinline__ float wave_sum(float v) {
    #pragma unroll
    for (int o = 32; o; o >>= 1) v += __shfl_down(v, o, 64);
    return v;
}
__device__ __forceinline__ float wave_max(float v) {
    #pragma unroll
    for (int o = 32; o; o >>= 1) v = fmaxf(v, __shfl_down(v, o, 64));
    return v;
}

// Row L2 norms: one wave per row.
__global__ __launch_bounds__(64) void norms_kernel(const float* __restrict__ X, int cols,
                                                   float* __restrict__ nrm) {
    const int row = blockIdx.x;
    const float* x = X + (size_t)row * cols;
    float s = 0.f;
    for (int c = threadIdx.x; c < cols; c += 64) { float v = x[c]; s += v * v; }
    s = wave_sum(s);
    if (threadIdx.x == 0) nrm[row] = sqrtf(s);
}

// 32x32 tiled transpose (used only for the 128x128 W matrices).
__global__ __launch_bounds__(256) void transpose_kernel(const float* __restrict__ X, int rows,
                                                        int cols, float* __restrict__ Xt) {
    __shared__ float tile[32][33];
    const int c0 = blockIdx.x * 32, r0 = blockIdx.y * 32;
    const int tx = threadIdx.x & 31, ty = threadIdx.x >> 5;
    #pragma unroll
    for (int rr = ty; rr < 32; rr += 8) {
        int c = c0 + tx;
        if (c < cols) tile[rr][tx] = X[(size_t)(r0 + rr) * cols + c];
    }
    __syncthreads();
    #pragma unroll
    for (int rr = ty; rr < 32; rr += 8) {
        int c = c0 + rr;
        if (c < cols) Xt[(size_t)c * rows + (r0 + tx)] = tile[tx][rr];
    }
}

// sim[i][j] = dot(A_i,A_j) / max(|A_i||A_j|, eps) * invtemp — tiled Gram.
// Grid 24x24, 256 threads, 32x32 output tile, 2x2 per thread.
// LDS tiles stored transposed ([k][row]) so compute reads are float2, conflict-free.
template <int COLS>
__global__ __launch_bounds__(256) void gram_kernel(const float* __restrict__ A,
                                                   const float* __restrict__ nrm,
                                                   float invtemp, float* __restrict__ sim) {
    __shared__ float As[32][34];
    __shared__ float Bs[32][34];
    const int tid = threadIdx.x;
    const int i0 = blockIdx.y * 32, j0 = blockIdx.x * 32;
    const int tx = tid & 15, ty = tid >> 4;
    const int lr = tid >> 3, lc4 = (tid & 7) * 4;
    float acc00 = 0.f, acc01 = 0.f, acc10 = 0.f, acc11 = 0.f;
    for (int kc = 0; kc < COLS; kc += 32) {
        float4 av, bv;
        if (kc + lc4 + 4 <= COLS) {
            av = *(const float4*)(A + (size_t)(i0 + lr) * COLS + kc + lc4);
            bv = *(const float4*)(A + (size_t)(j0 + lr) * COLS + kc + lc4);
        } else {
            float ta[4], tb[4];
            #pragma unroll
            for (int l = 0; l < 4; ++l) {
                int c = kc + lc4 + l;
                ta[l] = (c < COLS) ? A[(size_t)(i0 + lr) * COLS + c] : 0.f;
                tb[l] = (c < COLS) ? A[(size_t)(j0 + lr) * COLS + c] : 0.f;
            }
            av = make_float4(ta[0], ta[1], ta[2], ta[3]);
            bv = make_float4(tb[0], tb[1], tb[2], tb[3]);
        }
        __syncthreads();
        As[lc4 + 0][lr] = av.x; As[lc4 + 1][lr] = av.y;
        As[lc4 + 2][lr] = av.z; As[lc4 + 3][lr] = av.w;
        Bs[lc4 + 0][lr] = bv.x; Bs[lc4 + 1][lr] = bv.y;
        Bs[lc4 + 2][lr] = bv.z; Bs[lc4 + 3][lr] = bv.w;
        __syncthreads();
        #pragma unroll
        for (int k = 0; k < 32; ++k) {
            float2 a = *(const float2*)&As[k][2 * ty];
            float2 b = *(const float2*)&Bs[k][2 * tx];
            acc00 = fmaf(a.x, b.x, acc00);
            acc01 = fmaf(a.x, b.y, acc01);
            acc10 = fmaf(a.y, b.x, acc10);
            acc11 = fmaf(a.y, b.y, acc11);
        }
    }
    const float ni0 = nrm[i0 + 2 * ty], ni1 = nrm[i0 + 2 * ty + 1];
    const float nj0 = nrm[j0 + 2 * tx], nj1 = nrm[j0 + 2 * tx + 1];
    float* s0 = sim + (size_t)(i0 + 2 * ty) * NN + j0 + 2 * tx;
    float* s1 = s0 + NN;
    s0[0] = acc00 / fmaxf(ni0 * nj0, CEPS) * invtemp;
    s0[1] = acc01 / fmaxf(ni0 * nj1, CEPS) * invtemp;
    s1[0] = acc10 / fmaxf(ni1 * nj0, CEPS) * invtemp;
    s1[1] = acc11 / fmaxf(ni1 * nj1, CEPS) * invtemp;
}

// Row softmax over 768 columns; one block per row, 3 cols per thread.
__global__ __launch_bounds__(256) void softmax_kernel(const float* __restrict__ V,
                                                      float* __restrict__ E) {
    const int i = blockIdx.x, tid = threadIdx.x;
    __shared__ float redA[4], redB[4];
    const float* vr = V + (size_t)i * NN;
    float v0 = vr[tid], v1 = vr[tid + 256], v2 = vr[tid + 512];
    float m = wave_max(fmaxf(fmaxf(v0, v1), v2));
    if ((tid & 63) == 0) redA[tid >> 6] = m;
    __syncthreads();
    m = fmaxf(fmaxf(redA[0], redA[1]), fmaxf(redA[2], redA[3]));
    float e0 = __expf(v0 - m), e1 = __expf(v1 - m), e2 = __expf(v2 - m);
    float s = wave_sum(e0 + e1 + e2);
    if ((tid & 63) == 0) redB[tid >> 6] = s;
    __syncthreads();
    s = redB[0] + redB[1] + redB[2] + redB[3];
    const float inv = 1.f / s;
    float* er = E + (size_t)i * NN;
    er[tid] = e0 * inv;
    er[tid + 256] = e1 * inv;
    er[tid + 512] = e2 * inv;
}

// out = relu(LN((Ep@P + Ex@P) @ W^T + b)) + Ep@P.
// 512 threads = (k-split s: 0..3) x (d: 0..127); 2 rows per block; 384 blocks.
__global__ __launch_bounds__(512) void node_update_kernel(
    const float* __restrict__ P, const float* __restrict__ Ep, const float* __restrict__ Ex,
    const float* __restrict__ WT, const float* __restrict__ b, const float* __restrict__ g,
    const float* __restrict__ beta, float* __restrict__ out, float* __restrict__ outT) {
    const int i0 = blockIdx.x * 2;
    const int tid = threadIdx.x;
    const int s = tid >> 7, d = tid & 127;
    __shared__ float ep0[NN], ex0[NN], ep1[NN], ex1[NN];
    __shared__ float pp[4][2][DD], xx[4][2][DD];
    __shared__ float qs[2][DD], tps[2][2][DD];
    __shared__ float red[8], red2[8];
    for (int k = tid; k < NN; k += 512) {
        ep0[k] = Ep[(size_t)i0 * NN + k];
        ex0[k] = Ex[(size_t)i0 * NN + k];
        ep1[k] = Ep[(size_t)(i0 + 1) * NN + k];
        ex1[k] = Ex[(size_t)(i0 + 1) * NN + k];
    }
    __syncthreads();
    float p0 = 0.f, x0 = 0.f, p1 = 0.f, x1 = 0.f;
    const int kb = s * 192;
    #pragma unroll 4
    for (int kk = 0; kk < 192; ++kk) {
        const int k = kb + kk;
        const float pv = P[(size_t)k * DD + d];
        p0 = fmaf(ep0[k], pv, p0);
        x0 = fmaf(ex0[k], pv, x0);
        p1 = fmaf(ep1[k], pv, p1);
        x1 = fmaf(ex1[k], pv, x1);
    }
    pp[s][0][d] = p0; xx[s][0][d] = x0;
    pp[s][1][d] = p1; xx[s][1][d] = x1;
    __syncthreads();
    float preg = 0.f;
    const int rr = (tid >> 7) & 1;
    if (tid < 256) {
        float p = pp[0][rr][d] + pp[1][rr][d] + pp[2][rr][d] + pp[3][rr][d];
        float x = xx[0][rr][d] + xx[1][rr][d] + xx[2][rr][d] + xx[3][rr][d];
        qs[rr][d] = p + x;
        preg = p;
    }
    __syncthreads();
    {   // projection: (sc: 0..1) x (rr2: 0..1) x d
        const int sc = tid >> 8, rr2 = (tid >> 7) & 1;
        float t = (sc == 0) ? b[d] : 0.f;
        const int c0 = sc * 64;
        #pragma unroll 4
        for (int c = c0; c < c0 + 64; ++c)
            t = fmaf(qs[rr2][c], WT[(size_t)c * DD + d], t);
        tps[sc][rr2][d] = t;
    }
    __syncthreads();
    float tval = 0.f;
    if (tid < 256) tval = tps[0][rr][d] + tps[1][rr][d];
    float sm = wave_sum(tid < 256 ? tval : 0.f);
    if ((tid & 63) == 0) red[tid >> 6] = sm;
    __syncthreads();
    if (tid < 256) tval -= (red[2 * rr] + red[2 * rr + 1]) * (1.f / DD);
    float s2 = wave_sum(tid < 256 ? tval * tval : 0.f);
    if ((tid & 63) == 0) red2[tid >> 6] = s2;
    __syncthreads();
    if (tid < 256) {
        const float var = (red2[2 * rr] + red2[2 * rr + 1]) * (1.f / DD);
        const float ln = tval * rsqrtf(var + 1e-5f) * g[d] + beta[d];
        const float val = fmaxf(ln, 0.f) + preg;
        out[(size_t)(i0 + rr) * DD + d] = val;
        outT[(size_t)d * NN + i0 + rr] = val;
    }
}

__device__ __forceinline__ float edge_mlp_tail(float* z, const float* __restrict__ b1,
                                               const float* __restrict__ W2, float b2s) {
    float mean = 0.f;
    #pragma unroll
    for (int r = 0; r < HH; ++r) { z[r] += b1[r]; mean += z[r]; }
    mean *= (1.f / HH);
    float var = 0.f;
    #pragma unroll
    for (int r = 0; r < HH; ++r) { float dv = z[r] - mean; var += dv * dv; }
    var *= (1.f / HH);
    const float istd = rsqrtf(var + 1e-5f);
    float acc = b2s;
    #pragma unroll
    for (int r = 0; r < HH; ++r) {
        float hn = fmaxf((z[r] - mean) * istd, 0.f);
        acc = fmaf(hn, W2[r], acc);
    }
    return tanhf(acc);
}

// E2[i,:] = softmax(tanh(MLP((p_i - p_j)^2)) * (lastE[i,:]+eps) * invtemp). Block per row i.
__global__ __launch_bounds__(256) void edge_update_kernel(
    const float* __restrict__ PR, const float* __restrict__ PRt, const float* __restrict__ lastE,
    const float* __restrict__ W1, const float* __restrict__ b1, const float* __restrict__ W2,
    const float* __restrict__ b2, float invtemp, float* __restrict__ E2) {
    const int i = blockIdx.x;
    const int tid = threadIdx.x;
    __shared__ float pi[DD];
    __shared__ float4 w_s[HH][DD / 4];
    __shared__ float redA[4], redB[4];
    if (tid < DD) pi[tid] = PR[(size_t)i * DD + tid];
    ((float4*)w_s)[tid] = ((const float4*)W1)[tid];  // 256 float4 = all of W1
    __syncthreads();
    const int j0 = tid, j1 = tid + 256, j2 = tid + 512;
    float z0[HH], z1[HH], z2[HH];
    #pragma unroll
    for (int r = 0; r < HH; ++r) { z0[r] = 0.f; z1[r] = 0.f; z2[r] = 0.f; }
    const float4* p4 = (const float4*)pi;
    #pragma unroll 2
    for (int k4 = 0; k4 < DD / 4; ++k4) {
        const float4 pv = p4[k4];
        const float* r0 = PRt + (size_t)(k4 * 4) * NN;
        const float* r1 = r0 + NN;
        const float* r2 = r1 + NN;
        const float* r3 = r2 + NN;
        float q00 = pv.x - r0[j0]; q00 *= q00;
        float q10 = pv.x - r0[j1]; q10 *= q10;
        float q20 = pv.x - r0[j2]; q20 *= q20;
        float q01 = pv.y - r1[j0]; q01 *= q01;
        float q11 = pv.y - r1[j1]; q11 *= q11;
        float q21 = pv.y - r1[j2]; q21 *= q21;
        float q02 = pv.z - r2[j0]; q02 *= q02;
        float q12 = pv.z - r2[j1]; q12 *= q12;
        float q22 = pv.z - r2[j2]; q22 *= q22;
        float q03 = pv.w - r3[j0]; q03 *= q03;
        float q13 = pv.w - r3[j1]; q13 *= q13;
        float q23 = pv.w - r3[j2]; q23 *= q23;
        #pragma unroll
        for (int r = 0; r < HH; ++r) {
            const float4 w = w_s[r][k4];
            z0[r] += w.x * q00 + w.y * q01 + w.z * q02 + w.w * q03;
            z1[r] += w.x * q10 + w.y * q11 + w.z * q12 + w.w * q13;
            z2[r] += w.x * q20 + w.y * q21 + w.z * q22 + w.w * q23;
        }
    }
    const float b2s = b2[0];
    const float* lrow = lastE + (size_t)i * NN;
    float v0 = edge_mlp_tail(z0, b1, W2, b2s) * (lrow[j0] + CEPS) * invtemp;
    float v1 = edge_mlp_tail(z1, b1, W2, b2s) * (lrow[j1] + CEPS) * invtemp;
    float v2 = edge_mlp_tail(z2, b1, W2, b2s) * (lrow[j2] + CEPS) * invtemp;
    float m = wave_max(fmaxf(fmaxf(v0, v1), v2));
    if ((tid & 63) == 0) redA[tid >> 6] = m;
    __syncthreads();
    m = fmaxf(fmaxf(redA[0], redA[1]), fmaxf(redA[2], redA[3]));
    float e0 = __expf(v0 - m), e1 = __expf(v1 - m), e2 = __expf(v2 - m);
    float s = wave_sum(e0 + e1 + e2);
    if ((tid & 63) == 0) redB[tid >> 6] = s;
    __syncthreads();
    s = redB[0] + redB[1] + redB[2] + redB[3];
    const float inv = 1.f / s;
    float* Er = E2 + (size_t)i * NN;
    Er[j0] = e0 * inv;
    Er[j1] = e1 * inv;
    Er[j2] = e2 * inv;
}

extern "C" void kernel_launch(void* const* d_in, const int* in_sizes, int n_in, void* d_out,
                              int out_size, void* d_ws, size_t ws_size, hipStream_t stream) {
    const float* visual    = (const float*)d_in[0];
    const float* semantic  = (const float*)d_in[1];
    const float* attribute = (const float*)d_in[2];
    const float* Wvn  = (const float*)d_in[3];
    const float* bvn  = (const float*)d_in[4];
    const float* gvn  = (const float*)d_in[5];
    const float* betavn = (const float*)d_in[6];
    const float* Wve1 = (const float*)d_in[7];
    const float* bve1 = (const float*)d_in[8];
    const float* Wve2 = (const float*)d_in[9];
    const float* bve2 = (const float*)d_in[10];
    const float* Wsn  = (const float*)d_in[11];
    const float* bsn  = (const float*)d_in[12];
    const float* gsn  = (const float*)d_in[13];
    const float* betasn = (const float*)d_in[14];
    const float* Wse1 = (const float*)d_in[15];
    const float* bse1 = (const float*)d_in[16];
    const float* Wse2 = (const float*)d_in[17];
    const float* bse2 = (const float*)d_in[18];

    float* out = (float*)d_out;
    float* vp  = out;              // 768*128
    float* sp  = out + 98304;      // 768*128
    float* ve2 = out + 196608;     // 768*768
    float* se2 = out + 786432;     // 768*768

    float* ws    = (float*)d_ws;
    float* nrm_v = ws;             // 768
    float* nrm_a = ws + 768;       // 768
    float* simv  = ws + 1536;      // 768*768
    float* sima  = ws + 591360;    // 768*768
    float* ve    = ws + 1181184;   // 768*768
    float* se    = ws + 1771008;   // 768*768
    float* vpT   = ws + 2360832;   // 128*768
    float* spT   = ws + 2459136;   // 128*768
    float* WvnT  = ws + 2557440;   // 128*128
    float* WsnT  = ws + 2573824;   // 128*128

    norms_kernel<<<NN, 64, 0, stream>>>(visual, DD, nrm_v);
    norms_kernel<<<NN, 64, 0, stream>>>(attribute, AA, nrm_a);
    transpose_kernel<<<dim3(4, 4), 256, 0, stream>>>(Wvn, DD, DD, WvnT);
    transpose_kernel<<<dim3(4, 4), 256, 0, stream>>>(Wsn, DD, DD, WsnT);

    gram_kernel<DD><<<dim3(24, 24), 256, 0, stream>>>(visual, nrm_v, 10.f, simv);
    gram_kernel<AA><<<dim3(24, 24), 256, 0, stream>>>(attribute, nrm_a, 10.f, sima);
    softmax_kernel<<<NN, 256, 0, stream>>>(simv, ve);
    softmax_kernel<<<NN, 256, 0, stream>>>(sima, se);

    node_update_kernel<<<NN / 2, 512, 0, stream>>>(visual, ve, se, WvnT, bvn, gvn, betavn, vp, vpT);
    edge_update_kernel<<<NN, 256, 0, stream>>>(vp, vpT, ve, Wve1, bve1, Wve2, bve2, 0.1f, ve2);
    node_update_kernel<<<NN / 2, 512, 0, stream>>>(semantic, se, ve2, WsnT, bsn, gsn, betasn, sp, spT);
    edge_update_kernel<<<NN, 256, 0, stream>>>(sp, spT, se, Wse1, bse1, Wse2, bse2, 0.1f, se2);
}